// Round 11
// baseline (475.711 us; speedup 1.0000x reference)
//
#include <hip/hip_runtime.h>

// Problem constants (from reference)
#define V_ 12
#define N_ 80000
#define C_ 256
#define H_ 128
#define W_ 128
#define G_ 4096
#define M_ 512
#define E_ 200000
#define L_ 20
#define HD 128            // C/2 hidden dim
#define NROW (V_ * H_)    // row-buckets: (v, y) ; 1536
#define RCAP 128          // max items per row-bucket (Binomial λ=32; P(>128) ~ 0)
#define PCAP 32           // max pairs per point (Poisson λ=2.5; P(>=32) ~ 1e-19)
#define GV (G_ * V_)
#define QCH 64            // channels per gather block (quarter of C)
// Zero-init region: msum[M*C] + mcnt[M] + rcount[NROW] + pcount[N] (contiguous)
#define NZERO (M_ * C_ + M_ + NROW + N_)   // 213,120 words (mult of 4)

// ---------------------------------------------------------------------------
// Kernel 0: zero the accumulator/counter region with plain stores.
__global__ void init_kernel(float4* __restrict__ z) {
  int i = blockIdx.x * blockDim.x + threadIdx.x;
  if (i < NZERO / 4) z[i] = make_float4(0.f, 0.f, 0.f, 0.f);
}

// ---------------------------------------------------------------------------
// Kernel 1: build both inverted indexes in one pass.
__global__ void build_kernel(const float* __restrict__ is_seen,
                             const int* __restrict__ coords,
                             const int* __restrict__ centers,
                             const int* __restrict__ g2m,
                             const int* __restrict__ pair_mask,
                             const int* __restrict__ pair_point,
                             int* __restrict__ rcount,
                             int* __restrict__ rmeta,
                             float* __restrict__ rscale,
                             int* __restrict__ pcount,
                             int* __restrict__ pitems,
                             float* __restrict__ mcnt) {
  int t = blockIdx.x * blockDim.x + threadIdx.x;
  if (t < GV) {
    int g = t & (G_ - 1);   // g fast -> coalesced-ish centers reads
    int v = t >> 12;
    int n = centers[g];
    float wsum = 0.f;
#pragma unroll
    for (int vv = 0; vv < V_; ++vv) wsum += is_seen[(size_t)vv * N_ + n];
    float s = is_seen[(size_t)v * N_ + n] / (wsum + 1e-6f);
    if (v == 0) atomicAdd(&mcnt[g2m[g]], 1.0f);
    int x = coords[((size_t)v * N_ + n) * 2 + 0];
    int y = coords[((size_t)v * N_ + n) * 2 + 1];
    int b = (v << 7) | y;
    int slot = atomicAdd(&rcount[b], 1);
    if (slot < RCAP) {
      rmeta[b * RCAP + slot] = g | (x << 12);  // g:12 bits, x:7 bits
      rscale[b * RCAP + slot] = s;
    }
  } else if (t < GV + E_) {
    int e = t - GV;
    int p = pair_point[e];
    int slot = atomicAdd(&pcount[p], 1);
    if (slot < PCAP) pitems[(size_t)p * PCAP + slot] = pair_mask[e];
  }
}

// ---------------------------------------------------------------------------
// Kernel 2: row-bucket gather, ATOMIC-FREE + INSTRUCTION-COALESCED.
// IDEMPOTENT (pvg written exactly once per item, slot-order independent).
__global__ void gather_kernel(const float* __restrict__ img,
                              const int* __restrict__ rcount,
                              const int* __restrict__ rmeta,
                              const float* __restrict__ rscale,
                              float* __restrict__ pvg) {
  int bid = blockIdx.x;
  int b = bid >> 2;            // row-bucket (v,y)
  int cg = bid & 3;            // channel quarter: ch in [cg*64, cg*64+64)
  int cnt = rcount[b];
  if (cnt == 0) return;        // uniform branch
  if (cnt > RCAP) cnt = RCAP;
  int v = b >> 7;
  int y = b & 127;
  int t = threadIdx.x;
  __shared__ float rows[QCH * 129];  // 64 channels x 128 floats, pad stride 129
  const float4* base = (const float4*)(img +
      (((size_t)v * C_ + cg * QCH) * H_ + y) * W_);
#pragma unroll
  for (int i = 0; i < 8; ++i) {
    int f4 = i * 256 + t;      // flat float4 index over the 64x32 f4 slab
    int ch = f4 >> 5;          // 32 float4 per channel row
    int xo4 = f4 & 31;
    float4 u = base[(size_t)ch * (H_ * W_ / 4) + xo4];
    float* dst = &rows[ch * 129 + xo4 * 4];
    dst[0] = u.x; dst[1] = u.y; dst[2] = u.z; dst[3] = u.w;
  }
  __syncthreads();
  int w = t >> 6;
  int lane = t & 63;
  for (int it = w; it < cnt; it += 4) {
    int meta = rmeta[b * RCAP + it];
    float s = rscale[b * RCAP + it];
    int g = meta & 4095;
    int x = (meta >> 12) & 127;
    float val = rows[lane * 129 + x] * s;   // Δ129 per lane -> conflict-free
    pvg[((size_t)g * V_ + v) * C_ + cg * QCH + lane] = val;
  }
}

// ---------------------------------------------------------------------------
// Kernel 2b: per-group view reduction (1M coalesced atomics into msum).
// PROBE NOTE: dispatched 4x this round -> msum accumulates 4x the true sum;
// compensated exactly by cscale=0.25 in maskw1.
__global__ void greduce_kernel(const float* __restrict__ pvg,
                               const int* __restrict__ g2m,
                               float* __restrict__ msum) {
  int g = blockIdx.x;        // 0..G-1
  int t = threadIdx.x;       // 0..255
  __shared__ float buf[V_ * C_];   // 3072 floats = 12 KB
  const float4* src = (const float4*)(pvg + (size_t)g * V_ * C_);
  float4* bf4 = (float4*)buf;
#pragma unroll
  for (int i = 0; i < 3; ++i) bf4[i * 256 + t] = src[i * 256 + t];
  __syncthreads();
  float s = 0.f;
#pragma unroll
  for (int v = 0; v < V_; ++v) s += buf[v * C_ + t];
  atomicAdd(&msum[(size_t)g2m[g] * C_ + t], s);
}

// ---------------------------------------------------------------------------
// Kernel 3: mW1[m] = (where(mcnt>0, cscale*msum/max(mcnt,1), 0)) @ W1
__global__ void maskw1_kernel(const float* __restrict__ msum,
                              const float* __restrict__ mcnt,
                              const float* __restrict__ W1,
                              float* __restrict__ mW1,
                              float cscale) {
  int m = blockIdx.x;        // 0..M-1
  int j = threadIdx.x;       // 0..HD-1
  __shared__ float row[C_];
  row[j] = msum[(size_t)m * C_ + j];
  row[j + HD] = msum[(size_t)m * C_ + j + HD];
  __syncthreads();
  float cv = mcnt[m];
  float inv = cv > 0.f ? cscale / fmaxf(cv, 1.0f) : 0.f;
  float acc = 0.f;
  for (int c = 0; c < C_; ++c) {
    acc += row[c] * W1[(size_t)c * HD + j];
  }
  mW1[(size_t)m * HD + j] = acc * inv;
}

// ---------------------------------------------------------------------------
// Kernel 4: one wave per point; relu(mean + b1); 128x20 matvec; write 20.
__global__ void point_mlp_kernel(const int* __restrict__ pcount,
                                 const int* __restrict__ pitems,
                                 const float* __restrict__ mW1,
                                 const float* __restrict__ b1,
                                 const float* __restrict__ W2,
                                 const float* __restrict__ b2,
                                 float* __restrict__ out) {
  int wave = threadIdx.x >> 6;
  int lane = threadIdx.x & 63;
  int p = blockIdx.x * 4 + wave;   // N = 80000 = 20000*4 exactly
  __shared__ float hbuf[4][130];
  int cnt = pcount[p];
  int k = cnt < PCAP ? cnt : PCAP;
  float hx = 0.f, hy = 0.f;
  const int* lst = &pitems[(size_t)p * PCAP];
  for (int it = 0; it < k; ++it) {
    int m = lst[it];
    float2 r = ((const float2*)(mW1 + (size_t)m * HD))[lane];
    hx += r.x;
    hy += r.y;
  }
  float invc = 1.0f / fmaxf((float)cnt, 1e-6f);
  hbuf[wave][2 * lane]     = fmaxf(hx * invc + b1[2 * lane], 0.f);
  hbuf[wave][2 * lane + 1] = fmaxf(hy * invc + b1[2 * lane + 1], 0.f);
  __syncthreads();
  if (lane < L_) {
    float o = b2[lane];
    const float* hb = hbuf[wave];
#pragma unroll 8
    for (int kk = 0; kk < HD; ++kk) o += hb[kk] * W2[kk * L_ + lane];
    out[(size_t)p * L_ + lane] = o;
  }
}

// ---------------------------------------------------------------------------
extern "C" void kernel_launch(void* const* d_in, const int* in_sizes, int n_in,
                              void* d_out, int out_size, void* d_ws, size_t ws_size,
                              hipStream_t stream) {
  const float* img      = (const float*)d_in[0];
  const float* is_seen  = (const float*)d_in[1];
  const float* W1       = (const float*)d_in[2];
  const float* b1       = (const float*)d_in[3];
  const float* W2       = (const float*)d_in[4];
  const float* b2       = (const float*)d_in[5];
  const int* coords     = (const int*)d_in[6];
  const int* centers    = (const int*)d_in[7];
  const int* g2m        = (const int*)d_in[8];
  const int* pair_mask  = (const int*)d_in[9];
  const int* pair_point = (const int*)d_in[10];
  float* out = (float*)d_out;

  // Workspace layout — identical to round 8:
  //   msum[M*C] | mcnt[M] | rcount[NROW] | pcount[N]     <- zeroed by init_kernel
  //   mW1[M*HD] | rscale[NROW*RCAP] | rmeta | pitems | pvg[GV*C]
  float* ws     = (float*)d_ws;
  float* msum   = ws;
  float* mcnt   = msum + (size_t)M_ * C_;
  int*   rcount = (int*)(mcnt + M_);
  int*   pcount = rcount + NROW;
  float* mW1    = (float*)(pcount + N_);
  float* rscale = mW1 + (size_t)M_ * HD;
  int*   rmeta  = (int*)(rscale + (size_t)NROW * RCAP);
  int*   pitems = rmeta + (size_t)NROW * RCAP;
  float* pvg    = (float*)(pitems + (size_t)N_ * PCAP);

  // ===== ATTRIBUTION PROBE =====
  // Graph = r8's graph with init/greduce/maskw1/point_mlp each dispatched 4x
  // (greduce's 4x msum compensated by cscale=0.25). build & gather stay 1x.
  // dur_us - 177.25 (r8) = 3 * (init + greduce + maskw1 + point_mlp).
  init_kernel<<<(NZERO / 4 + 255) / 256, 256, 0, stream>>>((float4*)ws);
  init_kernel<<<(NZERO / 4 + 255) / 256, 256, 0, stream>>>((float4*)ws);
  init_kernel<<<(NZERO / 4 + 255) / 256, 256, 0, stream>>>((float4*)ws);
  init_kernel<<<(NZERO / 4 + 255) / 256, 256, 0, stream>>>((float4*)ws);
  build_kernel<<<(GV + E_ + 255) / 256, 256, 0, stream>>>(
      is_seen, coords, centers, g2m, pair_mask, pair_point,
      rcount, rmeta, rscale, pcount, pitems, mcnt);
  gather_kernel<<<NROW * 4, 256, 0, stream>>>(img, rcount, rmeta, rscale, pvg);
  greduce_kernel<<<G_, 256, 0, stream>>>(pvg, g2m, msum);
  greduce_kernel<<<G_, 256, 0, stream>>>(pvg, g2m, msum);
  greduce_kernel<<<G_, 256, 0, stream>>>(pvg, g2m, msum);
  greduce_kernel<<<G_, 256, 0, stream>>>(pvg, g2m, msum);
  maskw1_kernel<<<M_, HD, 0, stream>>>(msum, mcnt, W1, mW1, 0.25f);
  maskw1_kernel<<<M_, HD, 0, stream>>>(msum, mcnt, W1, mW1, 0.25f);
  maskw1_kernel<<<M_, HD, 0, stream>>>(msum, mcnt, W1, mW1, 0.25f);
  maskw1_kernel<<<M_, HD, 0, stream>>>(msum, mcnt, W1, mW1, 0.25f);
  point_mlp_kernel<<<N_ / 4, 256, 0, stream>>>(pcount, pitems, mW1, b1, W2, b2, out);
  point_mlp_kernel<<<N_ / 4, 256, 0, stream>>>(pcount, pitems, mW1, b1, W2, b2, out);
  point_mlp_kernel<<<N_ / 4, 256, 0, stream>>>(pcount, pitems, mW1, b1, W2, b2, out);
  point_mlp_kernel<<<N_ / 4, 256, 0, stream>>>(pcount, pitems, mW1, b1, W2, b2, out);
}

// Round 12
// 141.760 us; speedup vs baseline: 3.3557x; 3.3557x over previous
//
#include <hip/hip_runtime.h>

// Problem constants (from reference)
#define V_ 12
#define N_ 80000
#define C_ 256
#define H_ 128
#define W_ 128
#define G_ 4096
#define M_ 512
#define E_ 200000
#define L_ 20
#define HD 128            // C/2 hidden dim
#define NROW (V_ * H_)    // row-buckets: (v, y) ; 1536
#define RCAP 128          // max items per row-bucket (Binomial λ=32; P(>128) ~ 0)
#define PCAP 32           // max pairs per point (Poisson λ=2.5; P(>=32) ~ 1e-19)
#define GV (G_ * V_)
#define GSEG (G_ * 16)    // build: 16-lane segment per group (12 active)
#define QCH 64            // channels per gather block (quarter of C)
// Zero-init region: msum[M*C] + mcnt[M] + rcount[NROW] + pcount[N] (contiguous)
#define NZERO (M_ * C_ + M_ + NROW + N_)   // 213,120 words (mult of 4)

// ---------------------------------------------------------------------------
// Kernel 0: zero the accumulator/counter region with plain stores.
__global__ void init_kernel(float4* __restrict__ z) {
  int i = blockIdx.x * blockDim.x + threadIdx.x;
  if (i < NZERO / 4) z[i] = make_float4(0.f, 0.f, 0.f, 0.f);
}

// ---------------------------------------------------------------------------
// Kernel 1: build both inverted indexes. SEGMENT-PARALLEL rewrite: 16 lanes
// per group (12 active, one per view) -> each lane issues ONE scattered
// is_seen read + ONE int2 coords read (~150K scattered requests total, was
// ~690K with the per-(g,v)-thread redundant wsum loop). wsum via 4-step
// __shfl_xor reduce over the 16-lane segment.
__global__ void build_kernel(const float* __restrict__ is_seen,
                             const int* __restrict__ coords,
                             const int* __restrict__ centers,
                             const int* __restrict__ g2m,
                             const int* __restrict__ pair_mask,
                             const int* __restrict__ pair_point,
                             int* __restrict__ rcount,
                             int* __restrict__ rmeta,
                             float* __restrict__ rscale,
                             int* __restrict__ pcount,
                             int* __restrict__ pitems,
                             float* __restrict__ mcnt) {
  int t = blockIdx.x * blockDim.x + threadIdx.x;
  if (t < GSEG) {
    int g = t >> 4;          // group
    int s = t & 15;          // segment lane; s<12 = view id
    int n = centers[g];      // 16 lanes same address -> broadcast
    float w = 0.f;
    int x = 0, y = 0;
    if (s < V_) {
      w = is_seen[(size_t)s * N_ + n];
      int2 xy = ((const int2*)coords)[(size_t)s * N_ + n];
      x = xy.x; y = xy.y;
    }
    float wsum = w;
    wsum += __shfl_xor(wsum, 1, 16);
    wsum += __shfl_xor(wsum, 2, 16);
    wsum += __shfl_xor(wsum, 4, 16);
    wsum += __shfl_xor(wsum, 8, 16);
    if (s == 0) atomicAdd(&mcnt[g2m[g]], 1.0f);
    if (s < V_) {
      float sc = w / (wsum + 1e-6f);
      int b = (s << 7) | y;
      int slot = atomicAdd(&rcount[b], 1);
      if (slot < RCAP) {
        rmeta[b * RCAP + slot] = g | (x << 12);  // g:12 bits, x:7 bits
        rscale[b * RCAP + slot] = sc;
      }
    }
  } else if (t < GSEG + E_) {
    int e = t - GSEG;
    int p = pair_point[e];
    int slot = atomicAdd(&pcount[p], 1);
    if (slot < PCAP) pitems[(size_t)p * PCAP + slot] = pair_mask[e];
  }
}

// ---------------------------------------------------------------------------
// Kernel 2: row-bucket gather, ATOMIC-FREE + INSTRUCTION-COALESCED (r8 form;
// measured 40.2us warm via the r10 duplicate-dispatch probe).
__global__ void gather_kernel(const float* __restrict__ img,
                              const int* __restrict__ rcount,
                              const int* __restrict__ rmeta,
                              const float* __restrict__ rscale,
                              float* __restrict__ pvg) {
  int bid = blockIdx.x;
  int b = bid >> 2;            // row-bucket (v,y)
  int cg = bid & 3;            // channel quarter: ch in [cg*64, cg*64+64)
  int cnt = rcount[b];
  if (cnt == 0) return;        // uniform branch
  if (cnt > RCAP) cnt = RCAP;
  int v = b >> 7;
  int y = b & 127;
  int t = threadIdx.x;
  __shared__ float rows[QCH * 129];  // 64 channels x 128 floats, pad stride 129
  const float4* base = (const float4*)(img +
      (((size_t)v * C_ + cg * QCH) * H_ + y) * W_);
#pragma unroll
  for (int i = 0; i < 8; ++i) {
    int f4 = i * 256 + t;      // flat float4 index over the 64x32 f4 slab
    int ch = f4 >> 5;          // 32 float4 per channel row
    int xo4 = f4 & 31;
    float4 u = base[(size_t)ch * (H_ * W_ / 4) + xo4];
    float* dst = &rows[ch * 129 + xo4 * 4];
    dst[0] = u.x; dst[1] = u.y; dst[2] = u.z; dst[3] = u.w;
  }
  __syncthreads();
  int w = t >> 6;
  int lane = t & 63;
  for (int it = w; it < cnt; it += 4) {
    int meta = rmeta[b * RCAP + it];
    float s = rscale[b * RCAP + it];
    int g = meta & 4095;
    int x = (meta >> 12) & 127;
    float val = rows[lane * 129 + x] * s;   // Δ129 per lane -> conflict-free
    pvg[((size_t)g * V_ + v) * C_ + cg * QCH + lane] = val;
  }
}

// ---------------------------------------------------------------------------
// Kernel 2b: per-group view reduction (1M coalesced atomics into msum).
__global__ void greduce_kernel(const float* __restrict__ pvg,
                               const int* __restrict__ g2m,
                               float* __restrict__ msum) {
  int g = blockIdx.x;        // 0..G-1
  int t = threadIdx.x;       // 0..255
  __shared__ float buf[V_ * C_];   // 3072 floats = 12 KB
  const float4* src = (const float4*)(pvg + (size_t)g * V_ * C_);
  float4* bf4 = (float4*)buf;
#pragma unroll
  for (int i = 0; i < 3; ++i) bf4[i * 256 + t] = src[i * 256 + t];
  __syncthreads();
  float s = 0.f;
#pragma unroll
  for (int v = 0; v < V_; ++v) s += buf[v * C_ + t];
  atomicAdd(&msum[(size_t)g2m[g] * C_ + t], s);
}

// ---------------------------------------------------------------------------
// Kernel 3: mW1[m] = (where(mcnt>0, msum/max(mcnt,1), 0)) @ W1   (512 x 128)
__global__ void maskw1_kernel(const float* __restrict__ msum,
                              const float* __restrict__ mcnt,
                              const float* __restrict__ W1,
                              float* __restrict__ mW1) {
  int m = blockIdx.x;        // 0..M-1
  int j = threadIdx.x;       // 0..HD-1
  __shared__ float row[C_];
  row[j] = msum[(size_t)m * C_ + j];
  row[j + HD] = msum[(size_t)m * C_ + j + HD];
  __syncthreads();
  float cv = mcnt[m];
  float inv = cv > 0.f ? 1.0f / fmaxf(cv, 1.0f) : 0.f;
  float acc = 0.f;
  for (int c = 0; c < C_; ++c) {
    acc += row[c] * W1[(size_t)c * HD + j];
  }
  mW1[(size_t)m * HD + j] = acc * inv;
}

// ---------------------------------------------------------------------------
// Kernel 4: point MLP, LDS-W2 rewrite. Block = 4 waves x 3 points = 12 points.
// W2 (10KB) staged in LDS ONCE per block (kills the 820MB of per-iteration L2
// reads that made the old version ~80us). Phase 1: per point, lanes gather
// ~2.5 mW1 rows (L2-resident) -> h into LDS. Phase 2: lane = pt*20+j (60/64
// active), 128-iter all-LDS dot (both reads broadcast/conflict-free).
__global__ void point_mlp_kernel(const int* __restrict__ pcount,
                                 const int* __restrict__ pitems,
                                 const float* __restrict__ mW1,
                                 const float* __restrict__ b1,
                                 const float* __restrict__ W2,
                                 const float* __restrict__ b2,
                                 float* __restrict__ out) {
  __shared__ float w2s[HD * L_];     // 2560 floats = 10 KB
  __shared__ float hl[4][3][130];    // per-wave, per-point hidden vectors
  int t = threadIdx.x;
  for (int i = t; i < HD * L_; i += 256) w2s[i] = W2[i];
  __syncthreads();
  int wave = t >> 6;
  int lane = t & 63;
  int pbase = blockIdx.x * 12 + wave * 3;
#pragma unroll
  for (int pt = 0; pt < 3; ++pt) {
    int p = pbase + pt;
    if (p < N_) {
      int cnt = pcount[p];
      int k = cnt < PCAP ? cnt : PCAP;
      const int* lst = &pitems[(size_t)p * PCAP];
      float hx = 0.f, hy = 0.f;
      for (int it = 0; it < k; ++it) {
        int m = lst[it];
        float2 r = ((const float2*)(mW1 + (size_t)m * HD))[lane];
        hx += r.x;
        hy += r.y;
      }
      float invc = 1.0f / fmaxf((float)cnt, 1e-6f);
      hl[wave][pt][2 * lane]     = fmaxf(hx * invc + b1[2 * lane], 0.f);
      hl[wave][pt][2 * lane + 1] = fmaxf(hy * invc + b1[2 * lane + 1], 0.f);
    }
  }
  __syncthreads();
  if (lane < 60) {
    int pt = lane / 20;        // 0..2
    int j  = lane - pt * 20;   // 0..19
    int p = pbase + pt;
    if (p < N_) {
      float o = b2[j];
      const float* hrow = hl[wave][pt];
#pragma unroll 8
      for (int kk = 0; kk < HD; ++kk) o += hrow[kk] * w2s[kk * L_ + j];
      out[(size_t)p * L_ + j] = o;
    }
  }
}

// ---------------------------------------------------------------------------
extern "C" void kernel_launch(void* const* d_in, const int* in_sizes, int n_in,
                              void* d_out, int out_size, void* d_ws, size_t ws_size,
                              hipStream_t stream) {
  const float* img      = (const float*)d_in[0];
  const float* is_seen  = (const float*)d_in[1];
  const float* W1       = (const float*)d_in[2];
  const float* b1       = (const float*)d_in[3];
  const float* W2       = (const float*)d_in[4];
  const float* b2       = (const float*)d_in[5];
  const int* coords     = (const int*)d_in[6];
  const int* centers    = (const int*)d_in[7];
  const int* g2m        = (const int*)d_in[8];
  const int* pair_mask  = (const int*)d_in[9];
  const int* pair_point = (const int*)d_in[10];
  float* out = (float*)d_out;

  // Workspace layout — zero-init region FIRST and contiguous:
  //   msum[M*C] | mcnt[M] | rcount[NROW] | pcount[N]     <- zeroed by init_kernel
  //   mW1[M*HD] | rscale[NROW*RCAP] | rmeta | pitems | pvg[GV*C]
  float* ws     = (float*)d_ws;
  float* msum   = ws;
  float* mcnt   = msum + (size_t)M_ * C_;
  int*   rcount = (int*)(mcnt + M_);
  int*   pcount = rcount + NROW;
  float* mW1    = (float*)(pcount + N_);
  float* rscale = mW1 + (size_t)M_ * HD;
  int*   rmeta  = (int*)(rscale + (size_t)NROW * RCAP);
  int*   pitems = rmeta + (size_t)NROW * RCAP;
  float* pvg    = (float*)(pitems + (size_t)N_ * PCAP);

  init_kernel<<<(NZERO / 4 + 255) / 256, 256, 0, stream>>>((float4*)ws);
  build_kernel<<<(GSEG + E_ + 255) / 256, 256, 0, stream>>>(
      is_seen, coords, centers, g2m, pair_mask, pair_point,
      rcount, rmeta, rscale, pcount, pitems, mcnt);
  gather_kernel<<<NROW * 4, 256, 0, stream>>>(img, rcount, rmeta, rscale, pvg);
  greduce_kernel<<<G_, 256, 0, stream>>>(pvg, g2m, msum);
  maskw1_kernel<<<M_, HD, 0, stream>>>(msum, mcnt, W1, mW1);
  point_mlp_kernel<<<(N_ + 11) / 12, 256, 0, stream>>>(
      pcount, pitems, mW1, b1, W2, b2, out);
}